// Round 1
// baseline (242.746 us; speedup 1.0000x reference)
//
#include <hip/hip_runtime.h>
#include <hip/hip_bf16.h>
#include <stdint.h>

typedef __attribute__((ext_vector_type(8))) short  short8;   // 8 bf16 (4 VGPR) MFMA A/B frag
typedef __attribute__((ext_vector_type(4))) short  short4v;
typedef __attribute__((ext_vector_type(4))) float  float4v;  // MFMA C/D frag

#define MFMA16(a, b, c) __builtin_amdgcn_mfma_f32_16x16x32_bf16((a), (b), (c), 0, 0, 0)

#define S_LEN  4096
#define NBATCH 4
#define EMB    1024
#define DD     64
#define NROWS  (NBATCH * S_LEN)  // 16384
#define SCL2   0.1803368801111204f  // (1/sqrt(64)) * log2(e), folded into Wq at wcvt

#define AS1 const __attribute__((address_space(1))) unsigned int*
#define AS3 __attribute__((address_space(3))) unsigned int*

static __device__ __forceinline__ short f2bf(float f) {
  uint32_t u = __float_as_uint(f);
  return (short)((u + 0x7FFFu + ((u >> 16) & 1u)) >> 16);
}
static __device__ __forceinline__ unsigned pk2(float a, float b) {
  union { __hip_bfloat162 h; unsigned u; } z;
  z.h = __float22bfloat162_rn(make_float2(a, b));
  return z.u;
}
static __device__ __forceinline__ short8 cvt8(float4v a, float4v b) {
  union { unsigned u[4]; short8 s; } z;
  z.u[0] = pk2(a[0], a[1]); z.u[1] = pk2(a[2], a[3]);
  z.u[2] = pk2(b[0], b[1]); z.u[3] = pk2(b[2], b[3]);
  return z.s;
}

// ============ Kernel 0: W fp32 -> bf16, reordered into 32-k panels ============
// Wb2 layout: [32 panels][192 rows][32 k] bf16; rows 0-63=Wq (pre-scaled by
// SCL2 -> scores arrive in log2 domain), 64-127=Wk, 128-191=Wv.
__global__ void wcvt_kernel(const float* __restrict__ Wq, const float* __restrict__ Wk,
                            const float* __restrict__ Wv, short* __restrict__ Wb2) {
  const int t   = blockIdx.x * 256 + threadIdx.x;  // 0..24575, 8 elems each
  const int row = t >> 7;
  const int k   = (t & 127) * 8;
  const float* src = (row < 64) ? (Wq + (size_t)row * EMB)
                   : (row < 128) ? (Wk + (size_t)(row - 64) * EMB)
                                 : (Wv + (size_t)(row - 128) * EMB);
  const float sc = (row < 64) ? SCL2 : 1.0f;
  float4v a = *(const float4v*)(src + k);
  float4v b = *(const float4v*)(src + k + 4);
#pragma unroll
  for (int i = 0; i < 4; ++i) { a[i] *= sc; b[i] *= sc; }
  *(short8*)(Wb2 + (((k >> 5) * 192 + row) << 5) + (k & 31)) = cvt8(a, b);
}

// ======================= Kernel 1: QKV projection GEMM =======================
// m97-style async GEMM: 512 blocks x 256 thr (2/CU), M-tile 32, BK=64.
// Both x (fp32) and W panels (bf16) staged via global_load_lds width=16 into
// double-buffered LDS; one barrier/step, next-stage DMA issued AFTER the
// barrier so it overlaps compute. (unchanged)
__global__ __launch_bounds__(256, 2) void qkv_kernel(
    const float* __restrict__ x, const short* __restrict__ Wb2,
    short* __restrict__ Qb, short* __restrict__ Kb, short* __restrict__ Vt) {
  __shared__ float As[2][2048];   // 2 x 8 KB  (32 rows x 64 k fp32, slot order)
  __shared__ short Bs[2][12288];  // 2 x 24 KB (2 panels x 192 x 32 bf16, identity)

  const int tid  = threadIdx.x;
  const int w    = tid >> 6;
  const int lane = tid & 63;
  const int ln   = lane & 15;
  const int quad = lane >> 4;
  const int m0   = blockIdx.x * 32;
  const int wr   = w & 1;
  const int wc   = w >> 1;

  const int tA0 = 2 * w, tA1 = 2 * w + 1;
  const float* xA0 = x + (size_t)(m0 + ((tA0 >> 2) << 4) + (lane >> 2)) * EMB
                       + ((tA0 & 3) * 4 + (lane & 3)) * 4;
  const float* xA1 = x + (size_t)(m0 + ((tA1 >> 2) << 4) + (lane >> 2)) * EMB
                       + ((tA1 & 3) * 4 + (lane & 3)) * 4;
  const short* wB = Wb2 + (size_t)(6 * w) * 512 + lane * 8;

#define STAGE(S, BUF) do {                                                      \
    __builtin_amdgcn_global_load_lds((AS1)(xA0 + (S) * 64),                     \
        (AS3)&As[BUF][tA0 * 256], 16, 0, 0);                                    \
    __builtin_amdgcn_global_load_lds((AS1)(xA1 + (S) * 64),                     \
        (AS3)&As[BUF][tA1 * 256], 16, 0, 0);                                    \
    _Pragma("unroll")                                                           \
    for (int j = 0; j < 6; ++j)                                                 \
      __builtin_amdgcn_global_load_lds((AS1)(wB + (size_t)(S) * 12288 + j * 512),\
          (AS3)&Bs[BUF][(6 * w + j) * 512], 16, 0, 0);                          \
  } while (0)

  const float4v zz = {0.f, 0.f, 0.f, 0.f};
  float4v acc[6] = {zz, zz, zz, zz, zz, zz};

  STAGE(0, 0);
  int buf = 0;
  for (int s = 0; s < 16; ++s) {
    __syncthreads();                       // drains this buf's DMA (vmcnt 0)
    if (s + 1 < 16) STAGE(s + 1, buf ^ 1); // overlaps with compute below
    short8 aF[2];
#pragma unroll
    for (int h = 0; h < 2; ++h) {
      const int ai = (wr * 4 + 2 * h + (quad >> 1)) * 256 + (ln * 4 + (quad & 1) * 2) * 4;
      const float4v lo = *(const float4v*)&As[buf][ai];
      const float4v hi = *(const float4v*)&As[buf][ai + 4];
      aF[h] = cvt8(lo, hi);
    }
#pragma unroll
    for (int f = 0; f < 6; ++f) {
      const int cf = wc * 6 + f;
      const short8 b0 = *(const short8*)&Bs[buf][(cf * 16 + ln) * 32 + quad * 8];
      const short8 b1 = *(const short8*)&Bs[buf][6144 + (cf * 16 + ln) * 32 + quad * 8];
      if (wc == 0 || f < 2) {
        acc[f] = MFMA16(aF[0], b0, acc[f]);
        acc[f] = MFMA16(aF[1], b1, acc[f]);
      } else {  // V frags: operand swap -> transposed output
        acc[f] = MFMA16(b0, aF[0], acc[f]);
        acc[f] = MFMA16(b1, aF[1], acc[f]);
      }
    }
    buf ^= 1;
  }
#undef STAGE

  const int b  = m0 >> 12;
  const int sb = m0 & (S_LEN - 1);
  if (wc == 0) {
#pragma unroll
    for (int f = 0; f < 6; ++f)
#pragma unroll
      for (int r = 0; r < 4; ++r) {
        const int row = m0 + wr * 16 + quad * 4 + r;
        if (f < 4) Qb[(size_t)row * DD + f * 16 + ln] = f2bf(acc[f][r]);
        else       Kb[(size_t)row * DD + (f - 4) * 16 + ln] = f2bf(acc[f][r]);
      }
  } else {
#pragma unroll
    for (int f = 0; f < 2; ++f)
#pragma unroll
      for (int r = 0; r < 4; ++r) {
        const int row = m0 + wr * 16 + quad * 4 + r;
        Kb[(size_t)row * DD + 32 + f * 16 + ln] = f2bf(acc[f][r]);
      }
#pragma unroll
    for (int f = 2; f < 6; ++f)
#pragma unroll
      for (int r = 0; r < 4; ++r) {
        const int d = (f - 2) * 16 + quad * 4 + r;
        Vt[((size_t)b * DD + d) * S_LEN + sb + wr * 16 + ln] = f2bf(acc[f][r]);
      }
  }
}

// ======================= Kernel 2: causal flash attention =======================
// 256 blocks x 1024 thr (16 waves). Band-paired (j, 127-j) phases -> uniform work.
// Round 8: widen block 512->1024 threads. Grid was 256 blocks = exactly 1
// block/CU, so only 8 waves/CU were resident (Occupancy 19%, MfmaUtil 7% --
// pure latency-bound). 16 waves/CU (4/SIMD, same 128-VGPR budget as the old
// (512,2) bound) halves the per-wave tile count and doubles latency hiding.
// LDS: 16 P-panels = 157,696 B <= 163,840 B.
#define PSTRW 76
#define NW    16

__global__ __launch_bounds__(1024, 4) void attn_kernel(
    const short* __restrict__ Qb, const short* __restrict__ Kb,
    const short* __restrict__ Vt, float* __restrict__ out) {
  __shared__ float sbuf[NW][32 * PSTRW];
  __shared__ float llds[NW][32];

  const int tid  = threadIdx.x;
  const int w    = tid >> 6;
  const int lane = tid & 63;
  const int ln   = lane & 15;
  const int quad = lane >> 4;
  const int g    = blockIdx.x;
  const int b    = g & 3;
  const int j    = g >> 2;
  const short* Kbase = Kb + (size_t)b * S_LEN * DD;
  const short* Vbase = Vt + (size_t)b * DD * S_LEN;
  float* pw = &sbuf[w][0];
  const float4v zz = {0.f, 0.f, 0.f, 0.f};

  for (int ph = 0; ph < 2; ++ph) {
    const int band = ph ? (127 - j) : j;
    const int qb   = band * 32;
    const int qg0  = b * S_LEN + qb;

    short8 aQ[2][2];
#pragma unroll
    for (int rfi = 0; rfi < 2; ++rfi)
#pragma unroll
      for (int h = 0; h < 2; ++h)
        aQ[rfi][h] = *(const short8*)(Qb + (size_t)(qg0 + rfi * 16 + ln) * DD + h * 32 + quad * 8);

    float4v o[2][4];
    float lp[2][4];
#pragma unroll
    for (int rfi = 0; rfi < 2; ++rfi)
#pragma unroll
      for (int d = 0; d < 4; ++d) { o[rfi][d] = zz; lp[rfi][d] = 0.f; }

    const int T = (qb + 95) >> 6;

    short8 Kc[4][2], Kn[4][2];
#pragma unroll
    for (int c = 0; c < 4; ++c)
#pragma unroll
      for (int h = 0; h < 2; ++h)
        Kc[c][h] = *(const short8*)(Kbase + (size_t)(w * 64 + c * 16 + ln) * DD + h * 32 + quad * 8);

    for (int it = w; it < T; it += NW) {
      const int kv0 = it * 64;
      short8 Vc[4][2];
#pragma unroll
      for (int d = 0; d < 4; ++d)
#pragma unroll
        for (int h = 0; h < 2; ++h)
          Vc[d][h] = *(const short8*)(Vbase + (size_t)(d * 16 + ln) * S_LEN + kv0 + h * 32 + quad * 8);

      float4v s[2][4];
#pragma unroll
      for (int rfi = 0; rfi < 2; ++rfi)
#pragma unroll
        for (int c = 0; c < 4; ++c) {
          s[rfi][c] = MFMA16(aQ[rfi][0], Kc[c][0], zz);
          s[rfi][c] = MFMA16(aQ[rfi][1], Kc[c][1], s[rfi][c]);
        }

      const int kvn = (it + NW < T) ? (it + NW) * 64 : 0;
#pragma unroll
      for (int c = 0; c < 4; ++c)
#pragma unroll
        for (int h = 0; h < 2; ++h)
          Kn[c][h] = *(const short8*)(Kbase + (size_t)(kvn + c * 16 + ln) * DD + h * 32 + quad * 8);

      // P = exp2(S) (scores pre-scaled to log2 domain); single v_exp_f32 each.
      // Mask branch is wave-uniform: only the diagonal tile takes it.
      if ((kv0 + 63) > qb) {
#pragma unroll
        for (int rfi = 0; rfi < 2; ++rfi)
#pragma unroll
          for (int c = 0; c < 4; ++c)
#pragma unroll
            for (int r = 0; r < 4; ++r) {
              float e = __builtin_amdgcn_exp2f(fminf(s[rfi][c][r], 60.0f));
              if (kv0 + c * 16 + ln > qb + rfi * 16 + quad * 4 + r) e = 0.f;
              s[rfi][c][r] = e;
            }
      } else {
#pragma unroll
        for (int rfi = 0; rfi < 2; ++rfi)
#pragma unroll
          for (int c = 0; c < 4; ++c)
#pragma unroll
            for (int r = 0; r < 4; ++r)
              s[rfi][c][r] = __builtin_amdgcn_exp2f(fminf(s[rfi][c][r], 60.0f));
      }

#pragma unroll
      for (int rfi = 0; rfi < 2; ++rfi) {
#pragma unroll
        for (int r = 0; r < 4; ++r)
          lp[rfi][r] += s[rfi][0][r] + s[rfi][1][r] + s[rfi][2][r] + s[rfi][3][r];
#pragma unroll
        for (int c = 0; c < 4; ++c)
#pragma unroll
          for (int r = 0; r < 4; ++r)
            pw[(rfi * 16 + quad * 4 + r) * PSTRW + c * 16 + ln] = s[rfi][c][r];
      }
      asm volatile("s_waitcnt lgkmcnt(0)" ::: "memory");
      short8 aP[2][2];
#pragma unroll
      for (int rfi = 0; rfi < 2; ++rfi)
#pragma unroll
        for (int h = 0; h < 2; ++h) {
          const float4v lo = *(const float4v*)&pw[(rfi * 16 + ln) * PSTRW + h * 32 + quad * 8];
          const float4v hi = *(const float4v*)&pw[(rfi * 16 + ln) * PSTRW + h * 32 + quad * 8 + 4];
          aP[rfi][h] = cvt8(lo, hi);
        }
#pragma unroll
      for (int rfi = 0; rfi < 2; ++rfi)
#pragma unroll
        for (int d = 0; d < 4; ++d) {
          o[rfi][d] = MFMA16(aP[rfi][0], Vc[d][0], o[rfi][d]);
          o[rfi][d] = MFMA16(aP[rfi][1], Vc[d][1], o[rfi][d]);
        }
#pragma unroll
      for (int c = 0; c < 4; ++c)
#pragma unroll
        for (int h = 0; h < 2; ++h)
          Kc[c][h] = Kn[c][h];
    }

#pragma unroll
    for (int rfi = 0; rfi < 2; ++rfi)
#pragma unroll
      for (int r = 0; r < 4; ++r) {
        float lr = lp[rfi][r];
        lr += __shfl_xor(lr, 1);
        lr += __shfl_xor(lr, 2);
        lr += __shfl_xor(lr, 4);
        lr += __shfl_xor(lr, 8);
        if (ln == 0) llds[w][rfi * 16 + quad * 4 + r] = lr;
#pragma unroll
        for (int d = 0; d < 4; ++d)
          pw[(rfi * 16 + quad * 4 + r) * 64 + d * 16 + ln] = o[rfi][d][r];
      }
    __syncthreads();

#pragma unroll
    for (int jj = 0; jj < 2; ++jj) {
      const int idx = tid + jj * 1024;
      const int row = idx >> 6, col = idx & 63;
      float sum = 0.f, lt = 0.f;
#pragma unroll
      for (int wi = 0; wi < NW; ++wi) {
        sum += sbuf[wi][row * 64 + col];
        lt  += llds[wi][row];
      }
      out[(size_t)(qg0 + row) * DD + col] = sum * __builtin_amdgcn_rcpf(lt);
    }
    __syncthreads();
  }
}

extern "C" void kernel_launch(void* const* d_in, const int* in_sizes, int n_in,
                              void* d_out, int out_size, void* d_ws, size_t ws_size,
                              hipStream_t stream) {
  const float* x  = (const float*)d_in[0];
  const float* Wq = (const float*)d_in[1];
  const float* Wk = (const float*)d_in[2];
  const float* Wv = (const float*)d_in[3];

  short* Qb  = (short*)d_ws;                       // 2 MB
  short* Kb  = Qb + (size_t)NROWS * DD;            // 2 MB
  short* Vt  = Kb + (size_t)NROWS * DD;            // 2 MB  [b][d][s]
  short* Wb2 = Vt + (size_t)NROWS * DD;            // 384 KB panels

  wcvt_kernel<<<dim3(96), dim3(256), 0, stream>>>(Wq, Wk, Wv, Wb2);
  qkv_kernel<<<dim3(NROWS / 32), dim3(256), 0, stream>>>(x, Wb2, Qb, Kb, Vt);
  attn_kernel<<<dim3(NBATCH * 64), dim3(1024), 0, stream>>>(Qb, Kb, Vt, (float*)d_out);
}

// Round 2
// 223.279 us; speedup vs baseline: 1.0872x; 1.0872x over previous
//
#include <hip/hip_runtime.h>
#include <hip/hip_bf16.h>
#include <stdint.h>

typedef __attribute__((ext_vector_type(8))) short  short8;   // 8 bf16 (4 VGPR) MFMA A/B frag
typedef __attribute__((ext_vector_type(4))) short  short4v;
typedef __attribute__((ext_vector_type(4))) float  float4v;  // MFMA C/D frag

#define MFMA16(a, b, c) __builtin_amdgcn_mfma_f32_16x16x32_bf16((a), (b), (c), 0, 0, 0)

#define S_LEN  4096
#define NBATCH 4
#define EMB    1024
#define DD     64
#define NROWS  (NBATCH * S_LEN)  // 16384
#define SCL2   0.1803368801111204f  // (1/sqrt(64)) * log2(e), folded into Wq at wcvt

#define AS1 const __attribute__((address_space(1))) unsigned int*
#define AS3 __attribute__((address_space(3))) unsigned int*

static __device__ __forceinline__ short f2bf(float f) {
  uint32_t u = __float_as_uint(f);
  return (short)((u + 0x7FFFu + ((u >> 16) & 1u)) >> 16);
}
static __device__ __forceinline__ unsigned pk2(float a, float b) {
  union { __hip_bfloat162 h; unsigned u; } z;
  z.h = __float22bfloat162_rn(make_float2(a, b));
  return z.u;
}
static __device__ __forceinline__ short8 cvt8(float4v a, float4v b) {
  union { unsigned u[4]; short8 s; } z;
  z.u[0] = pk2(a[0], a[1]); z.u[1] = pk2(a[2], a[3]);
  z.u[2] = pk2(b[0], b[1]); z.u[3] = pk2(b[2], b[3]);
  return z.s;
}

// ============ Kernel 0: W fp32 -> bf16, reordered into 32-k panels ============
// Wb2 layout: [32 panels][192 rows][32 k] bf16; rows 0-63=Wq (pre-scaled by
// SCL2 -> scores arrive in log2 domain), 64-127=Wk, 128-191=Wv.
__global__ void wcvt_kernel(const float* __restrict__ Wq, const float* __restrict__ Wk,
                            const float* __restrict__ Wv, short* __restrict__ Wb2) {
  const int t   = blockIdx.x * 256 + threadIdx.x;  // 0..24575, 8 elems each
  const int row = t >> 7;
  const int k   = (t & 127) * 8;
  const float* src = (row < 64) ? (Wq + (size_t)row * EMB)
                   : (row < 128) ? (Wk + (size_t)(row - 64) * EMB)
                                 : (Wv + (size_t)(row - 128) * EMB);
  const float sc = (row < 64) ? SCL2 : 1.0f;
  float4v a = *(const float4v*)(src + k);
  float4v b = *(const float4v*)(src + k + 4);
#pragma unroll
  for (int i = 0; i < 4; ++i) { a[i] *= sc; b[i] *= sc; }
  *(short8*)(Wb2 + (((k >> 5) * 192 + row) << 5) + (k & 31)) = cvt8(a, b);
}

// ======================= Kernel 1: QKV projection GEMM =======================
// m97-style async GEMM: 512 blocks x 256 thr (2/CU), M-tile 32, BK=64.
// Both x (fp32) and W panels (bf16) staged via global_load_lds width=16 into
// double-buffered LDS; one barrier/step, next-stage DMA issued AFTER the
// barrier so it overlaps compute. (unchanged)
__global__ __launch_bounds__(256, 2) void qkv_kernel(
    const float* __restrict__ x, const short* __restrict__ Wb2,
    short* __restrict__ Qb, short* __restrict__ Kb, short* __restrict__ Vt) {
  __shared__ float As[2][2048];   // 2 x 8 KB  (32 rows x 64 k fp32, slot order)
  __shared__ short Bs[2][12288];  // 2 x 24 KB (2 panels x 192 x 32 bf16, identity)

  const int tid  = threadIdx.x;
  const int w    = tid >> 6;
  const int lane = tid & 63;
  const int ln   = lane & 15;
  const int quad = lane >> 4;
  const int m0   = blockIdx.x * 32;
  const int wr   = w & 1;
  const int wc   = w >> 1;

  const int tA0 = 2 * w, tA1 = 2 * w + 1;
  const float* xA0 = x + (size_t)(m0 + ((tA0 >> 2) << 4) + (lane >> 2)) * EMB
                       + ((tA0 & 3) * 4 + (lane & 3)) * 4;
  const float* xA1 = x + (size_t)(m0 + ((tA1 >> 2) << 4) + (lane >> 2)) * EMB
                       + ((tA1 & 3) * 4 + (lane & 3)) * 4;
  const short* wB = Wb2 + (size_t)(6 * w) * 512 + lane * 8;

#define STAGE(S, BUF) do {                                                      \
    __builtin_amdgcn_global_load_lds((AS1)(xA0 + (S) * 64),                     \
        (AS3)&As[BUF][tA0 * 256], 16, 0, 0);                                    \
    __builtin_amdgcn_global_load_lds((AS1)(xA1 + (S) * 64),                     \
        (AS3)&As[BUF][tA1 * 256], 16, 0, 0);                                    \
    _Pragma("unroll")                                                           \
    for (int j = 0; j < 6; ++j)                                                 \
      __builtin_amdgcn_global_load_lds((AS1)(wB + (size_t)(S) * 12288 + j * 512),\
          (AS3)&Bs[BUF][(6 * w + j) * 512], 16, 0, 0);                          \
  } while (0)

  const float4v zz = {0.f, 0.f, 0.f, 0.f};
  float4v acc[6] = {zz, zz, zz, zz, zz, zz};

  STAGE(0, 0);
  int buf = 0;
  for (int s = 0; s < 16; ++s) {
    __syncthreads();                       // drains this buf's DMA (vmcnt 0)
    if (s + 1 < 16) STAGE(s + 1, buf ^ 1); // overlaps with compute below
    short8 aF[2];
#pragma unroll
    for (int h = 0; h < 2; ++h) {
      const int ai = (wr * 4 + 2 * h + (quad >> 1)) * 256 + (ln * 4 + (quad & 1) * 2) * 4;
      const float4v lo = *(const float4v*)&As[buf][ai];
      const float4v hi = *(const float4v*)&As[buf][ai + 4];
      aF[h] = cvt8(lo, hi);
    }
#pragma unroll
    for (int f = 0; f < 6; ++f) {
      const int cf = wc * 6 + f;
      const short8 b0 = *(const short8*)&Bs[buf][(cf * 16 + ln) * 32 + quad * 8];
      const short8 b1 = *(const short8*)&Bs[buf][6144 + (cf * 16 + ln) * 32 + quad * 8];
      if (wc == 0 || f < 2) {
        acc[f] = MFMA16(aF[0], b0, acc[f]);
        acc[f] = MFMA16(aF[1], b1, acc[f]);
      } else {  // V frags: operand swap -> transposed output
        acc[f] = MFMA16(b0, aF[0], acc[f]);
        acc[f] = MFMA16(b1, aF[1], acc[f]);
      }
    }
    buf ^= 1;
  }
#undef STAGE

  const int b  = m0 >> 12;
  const int sb = m0 & (S_LEN - 1);
  if (wc == 0) {
#pragma unroll
    for (int f = 0; f < 6; ++f)
#pragma unroll
      for (int r = 0; r < 4; ++r) {
        const int row = m0 + wr * 16 + quad * 4 + r;
        if (f < 4) Qb[(size_t)row * DD + f * 16 + ln] = f2bf(acc[f][r]);
        else       Kb[(size_t)row * DD + (f - 4) * 16 + ln] = f2bf(acc[f][r]);
      }
  } else {
#pragma unroll
    for (int f = 0; f < 2; ++f)
#pragma unroll
      for (int r = 0; r < 4; ++r) {
        const int row = m0 + wr * 16 + quad * 4 + r;
        Kb[(size_t)row * DD + 32 + f * 16 + ln] = f2bf(acc[f][r]);
      }
#pragma unroll
    for (int f = 2; f < 6; ++f)
#pragma unroll
      for (int r = 0; r < 4; ++r) {
        const int d = (f - 2) * 16 + quad * 4 + r;
        Vt[((size_t)b * DD + d) * S_LEN + sb + wr * 16 + ln] = f2bf(acc[f][r]);
      }
  }
}

// ======================= Kernel 2: causal flash attention =======================
// Round 9: back to the proven 512-thread / 120-VGPR / 78,848-B-LDS shape
// (round 8's 1024-thread block forced VGPR->64 and spilled K/V frags to
// scratch: 530 MB of scratch traffic, 3x regression). Occupancy now comes
// from the GRID: 512 blocks, one 32-row band each, __launch_bounds__(512,4)
// -> 2 blocks/CU (VGPR cap 128 >= 120, LDS 2x78848 <= 160K). Blocks G and
// G+256 get complementary bands (jj, 127-jj): under round-robin dispatch they
// co-reside on a CU with balanced total work; independent blocks overlap each
// other's exp/LDS/MFMA chains.
#define PSTRW 76

__global__ __launch_bounds__(512, 4) void attn_kernel(
    const short* __restrict__ Qb, const short* __restrict__ Kb,
    const short* __restrict__ Vt, float* __restrict__ out) {
  __shared__ float sbuf[8][32 * PSTRW];
  __shared__ float llds[8][32];

  const int tid  = threadIdx.x;
  const int w    = tid >> 6;
  const int lane = tid & 63;
  const int ln   = lane & 15;
  const int quad = lane >> 4;
  const int g    = blockIdx.x;
  const int u    = g & 255;
  const int half = g >> 8;
  const int b    = u & 3;
  const int jj   = u >> 2;
  const int band = half ? (127 - jj) : jj;
  const short* Kbase = Kb + (size_t)b * S_LEN * DD;
  const short* Vbase = Vt + (size_t)b * DD * S_LEN;
  float* pw = &sbuf[w][0];
  const float4v zz = {0.f, 0.f, 0.f, 0.f};

  const int qb  = band * 32;
  const int qg0 = b * S_LEN + qb;

  short8 aQ[2][2];
#pragma unroll
  for (int rfi = 0; rfi < 2; ++rfi)
#pragma unroll
    for (int h = 0; h < 2; ++h)
      aQ[rfi][h] = *(const short8*)(Qb + (size_t)(qg0 + rfi * 16 + ln) * DD + h * 32 + quad * 8);

  float4v o[2][4];
  float lp[2][4];
#pragma unroll
  for (int rfi = 0; rfi < 2; ++rfi)
#pragma unroll
    for (int d = 0; d < 4; ++d) { o[rfi][d] = zz; lp[rfi][d] = 0.f; }

  const int T = (qb + 95) >> 6;

  short8 Kc[4][2], Kn[4][2];
#pragma unroll
  for (int c = 0; c < 4; ++c)
#pragma unroll
    for (int h = 0; h < 2; ++h)
      Kc[c][h] = *(const short8*)(Kbase + (size_t)(w * 64 + c * 16 + ln) * DD + h * 32 + quad * 8);

  for (int it = w; it < T; it += 8) {
    const int kv0 = it * 64;
    short8 Vc[4][2];
#pragma unroll
    for (int d = 0; d < 4; ++d)
#pragma unroll
      for (int h = 0; h < 2; ++h)
        Vc[d][h] = *(const short8*)(Vbase + (size_t)(d * 16 + ln) * S_LEN + kv0 + h * 32 + quad * 8);

    float4v s[2][4];
#pragma unroll
    for (int rfi = 0; rfi < 2; ++rfi)
#pragma unroll
      for (int c = 0; c < 4; ++c) {
        s[rfi][c] = MFMA16(aQ[rfi][0], Kc[c][0], zz);
        s[rfi][c] = MFMA16(aQ[rfi][1], Kc[c][1], s[rfi][c]);
      }

    const int kvn = (it + 8 < T) ? (it + 8) * 64 : 0;
#pragma unroll
    for (int c = 0; c < 4; ++c)
#pragma unroll
      for (int h = 0; h < 2; ++h)
        Kn[c][h] = *(const short8*)(Kbase + (size_t)(kvn + c * 16 + ln) * DD + h * 32 + quad * 8);

    // P = exp2(S) (scores pre-scaled to log2 domain); single v_exp_f32 each.
    // Mask branch is wave-uniform: only the diagonal tile takes it.
    if ((kv0 + 63) > qb) {
#pragma unroll
      for (int rfi = 0; rfi < 2; ++rfi)
#pragma unroll
        for (int c = 0; c < 4; ++c)
#pragma unroll
          for (int r = 0; r < 4; ++r) {
            float e = __builtin_amdgcn_exp2f(fminf(s[rfi][c][r], 60.0f));
            if (kv0 + c * 16 + ln > qb + rfi * 16 + quad * 4 + r) e = 0.f;
            s[rfi][c][r] = e;
          }
    } else {
#pragma unroll
      for (int rfi = 0; rfi < 2; ++rfi)
#pragma unroll
        for (int c = 0; c < 4; ++c)
#pragma unroll
          for (int r = 0; r < 4; ++r)
            s[rfi][c][r] = __builtin_amdgcn_exp2f(fminf(s[rfi][c][r], 60.0f));
    }

#pragma unroll
    for (int rfi = 0; rfi < 2; ++rfi) {
#pragma unroll
      for (int r = 0; r < 4; ++r)
        lp[rfi][r] += s[rfi][0][r] + s[rfi][1][r] + s[rfi][2][r] + s[rfi][3][r];
#pragma unroll
      for (int c = 0; c < 4; ++c)
#pragma unroll
        for (int r = 0; r < 4; ++r)
          pw[(rfi * 16 + quad * 4 + r) * PSTRW + c * 16 + ln] = s[rfi][c][r];
    }
    asm volatile("s_waitcnt lgkmcnt(0)" ::: "memory");
    short8 aP[2][2];
#pragma unroll
    for (int rfi = 0; rfi < 2; ++rfi)
#pragma unroll
      for (int h = 0; h < 2; ++h) {
        const float4v lo = *(const float4v*)&pw[(rfi * 16 + ln) * PSTRW + h * 32 + quad * 8];
        const float4v hi = *(const float4v*)&pw[(rfi * 16 + ln) * PSTRW + h * 32 + quad * 8 + 4];
        aP[rfi][h] = cvt8(lo, hi);
      }
#pragma unroll
    for (int rfi = 0; rfi < 2; ++rfi)
#pragma unroll
      for (int d = 0; d < 4; ++d) {
        o[rfi][d] = MFMA16(aP[rfi][0], Vc[d][0], o[rfi][d]);
        o[rfi][d] = MFMA16(aP[rfi][1], Vc[d][1], o[rfi][d]);
      }
#pragma unroll
    for (int c = 0; c < 4; ++c)
#pragma unroll
      for (int h = 0; h < 2; ++h)
        Kc[c][h] = Kn[c][h];
  }

#pragma unroll
  for (int rfi = 0; rfi < 2; ++rfi)
#pragma unroll
    for (int r = 0; r < 4; ++r) {
      float lr = lp[rfi][r];
      lr += __shfl_xor(lr, 1);
      lr += __shfl_xor(lr, 2);
      lr += __shfl_xor(lr, 4);
      lr += __shfl_xor(lr, 8);
      if (ln == 0) llds[w][rfi * 16 + quad * 4 + r] = lr;
#pragma unroll
      for (int d = 0; d < 4; ++d)
        pw[(rfi * 16 + quad * 4 + r) * 64 + d * 16 + ln] = o[rfi][d][r];
    }
  __syncthreads();

#pragma unroll
  for (int jx = 0; jx < 4; ++jx) {
    const int idx = tid + jx * 512;
    const int row = idx >> 6, col = idx & 63;
    float sum = 0.f, lt = 0.f;
#pragma unroll
    for (int wi = 0; wi < 8; ++wi) {
      sum += sbuf[wi][row * 64 + col];
      lt  += llds[wi][row];
    }
    out[(size_t)(qg0 + row) * DD + col] = sum * __builtin_amdgcn_rcpf(lt);
  }
}

extern "C" void kernel_launch(void* const* d_in, const int* in_sizes, int n_in,
                              void* d_out, int out_size, void* d_ws, size_t ws_size,
                              hipStream_t stream) {
  const float* x  = (const float*)d_in[0];
  const float* Wq = (const float*)d_in[1];
  const float* Wk = (const float*)d_in[2];
  const float* Wv = (const float*)d_in[3];

  short* Qb  = (short*)d_ws;                       // 2 MB
  short* Kb  = Qb + (size_t)NROWS * DD;            // 2 MB
  short* Vt  = Kb + (size_t)NROWS * DD;            // 2 MB  [b][d][s]
  short* Wb2 = Vt + (size_t)NROWS * DD;            // 384 KB panels

  wcvt_kernel<<<dim3(96), dim3(256), 0, stream>>>(Wq, Wk, Wv, Wb2);
  qkv_kernel<<<dim3(NROWS / 32), dim3(256), 0, stream>>>(x, Wb2, Qb, Kb, Vt);
  attn_kernel<<<dim3(NBATCH * 128), dim3(512), 0, stream>>>(Qb, Kb, Vt, (float*)d_out);
}

// Round 3
// 158.935 us; speedup vs baseline: 1.5273x; 1.4048x over previous
//
#include <hip/hip_runtime.h>
#include <hip/hip_bf16.h>
#include <stdint.h>

typedef __attribute__((ext_vector_type(8))) short  short8;   // 8 bf16 (4 VGPR) MFMA A/B frag
typedef __attribute__((ext_vector_type(4))) short  short4v;
typedef __attribute__((ext_vector_type(4))) float  float4v;  // MFMA C/D frag

#define MFMA16(a, b, c) __builtin_amdgcn_mfma_f32_16x16x32_bf16((a), (b), (c), 0, 0, 0)

#define S_LEN  4096
#define NBATCH 4
#define EMB    1024
#define DD     64
#define NROWS  (NBATCH * S_LEN)  // 16384
#define SCL2   0.1803368801111204f  // (1/sqrt(64)) * log2(e), folded into Wq at wcvt

#define AS1 const __attribute__((address_space(1))) unsigned int*
#define AS3 __attribute__((address_space(3))) unsigned int*

static __device__ __forceinline__ short f2bf(float f) {
  uint32_t u = __float_as_uint(f);
  return (short)((u + 0x7FFFu + ((u >> 16) & 1u)) >> 16);
}
static __device__ __forceinline__ unsigned pk2(float a, float b) {
  union { __hip_bfloat162 h; unsigned u; } z;
  z.h = __float22bfloat162_rn(make_float2(a, b));
  return z.u;
}
static __device__ __forceinline__ short8 cvt8(float4v a, float4v b) {
  union { unsigned u[4]; short8 s; } z;
  z.u[0] = pk2(a[0], a[1]); z.u[1] = pk2(a[2], a[3]);
  z.u[2] = pk2(b[0], b[1]); z.u[3] = pk2(b[2], b[3]);
  return z.s;
}

// ============ Kernel 0: W fp32 -> bf16, reordered into 32-k panels ============
// Wb2 layout: [32 panels][192 rows][32 k] bf16; rows 0-63=Wq (pre-scaled by
// SCL2 -> scores arrive in log2 domain), 64-127=Wk, 128-191=Wv.
__global__ void wcvt_kernel(const float* __restrict__ Wq, const float* __restrict__ Wk,
                            const float* __restrict__ Wv, short* __restrict__ Wb2) {
  const int t   = blockIdx.x * 256 + threadIdx.x;  // 0..24575, 8 elems each
  const int row = t >> 7;
  const int k   = (t & 127) * 8;
  const float* src = (row < 64) ? (Wq + (size_t)row * EMB)
                   : (row < 128) ? (Wk + (size_t)(row - 64) * EMB)
                                 : (Wv + (size_t)(row - 128) * EMB);
  const float sc = (row < 64) ? SCL2 : 1.0f;
  float4v a = *(const float4v*)(src + k);
  float4v b = *(const float4v*)(src + k + 4);
#pragma unroll
  for (int i = 0; i < 4; ++i) { a[i] *= sc; b[i] *= sc; }
  *(short8*)(Wb2 + (((k >> 5) * 192 + row) << 5) + (k & 31)) = cvt8(a, b);
}

// ======================= Kernel 1: QKV projection GEMM =======================
// m97-style async GEMM: 512 blocks x 256 thr (2/CU), M-tile 32, BK=64.
// Both x (fp32) and W panels (bf16) staged via global_load_lds width=16 into
// double-buffered LDS; one barrier/step, next-stage DMA issued AFTER the
// barrier so it overlaps compute. (unchanged)
__global__ __launch_bounds__(256, 2) void qkv_kernel(
    const float* __restrict__ x, const short* __restrict__ Wb2,
    short* __restrict__ Qb, short* __restrict__ Kb, short* __restrict__ Vt) {
  __shared__ float As[2][2048];   // 2 x 8 KB  (32 rows x 64 k fp32, slot order)
  __shared__ short Bs[2][12288];  // 2 x 24 KB (2 panels x 192 x 32 bf16, identity)

  const int tid  = threadIdx.x;
  const int w    = tid >> 6;
  const int lane = tid & 63;
  const int ln   = lane & 15;
  const int quad = lane >> 4;
  const int m0   = blockIdx.x * 32;
  const int wr   = w & 1;
  const int wc   = w >> 1;

  const int tA0 = 2 * w, tA1 = 2 * w + 1;
  const float* xA0 = x + (size_t)(m0 + ((tA0 >> 2) << 4) + (lane >> 2)) * EMB
                       + ((tA0 & 3) * 4 + (lane & 3)) * 4;
  const float* xA1 = x + (size_t)(m0 + ((tA1 >> 2) << 4) + (lane >> 2)) * EMB
                       + ((tA1 & 3) * 4 + (lane & 3)) * 4;
  const short* wB = Wb2 + (size_t)(6 * w) * 512 + lane * 8;

#define STAGE(S, BUF) do {                                                      \
    __builtin_amdgcn_global_load_lds((AS1)(xA0 + (S) * 64),                     \
        (AS3)&As[BUF][tA0 * 256], 16, 0, 0);                                    \
    __builtin_amdgcn_global_load_lds((AS1)(xA1 + (S) * 64),                     \
        (AS3)&As[BUF][tA1 * 256], 16, 0, 0);                                    \
    _Pragma("unroll")                                                           \
    for (int j = 0; j < 6; ++j)                                                 \
      __builtin_amdgcn_global_load_lds((AS1)(wB + (size_t)(S) * 12288 + j * 512),\
          (AS3)&Bs[BUF][(6 * w + j) * 512], 16, 0, 0);                          \
  } while (0)

  const float4v zz = {0.f, 0.f, 0.f, 0.f};
  float4v acc[6] = {zz, zz, zz, zz, zz, zz};

  STAGE(0, 0);
  int buf = 0;
  for (int s = 0; s < 16; ++s) {
    __syncthreads();                       // drains this buf's DMA (vmcnt 0)
    if (s + 1 < 16) STAGE(s + 1, buf ^ 1); // overlaps with compute below
    short8 aF[2];
#pragma unroll
    for (int h = 0; h < 2; ++h) {
      const int ai = (wr * 4 + 2 * h + (quad >> 1)) * 256 + (ln * 4 + (quad & 1) * 2) * 4;
      const float4v lo = *(const float4v*)&As[buf][ai];
      const float4v hi = *(const float4v*)&As[buf][ai + 4];
      aF[h] = cvt8(lo, hi);
    }
#pragma unroll
    for (int f = 0; f < 6; ++f) {
      const int cf = wc * 6 + f;
      const short8 b0 = *(const short8*)&Bs[buf][(cf * 16 + ln) * 32 + quad * 8];
      const short8 b1 = *(const short8*)&Bs[buf][6144 + (cf * 16 + ln) * 32 + quad * 8];
      if (wc == 0 || f < 2) {
        acc[f] = MFMA16(aF[0], b0, acc[f]);
        acc[f] = MFMA16(aF[1], b1, acc[f]);
      } else {  // V frags: operand swap -> transposed output
        acc[f] = MFMA16(b0, aF[0], acc[f]);
        acc[f] = MFMA16(b1, aF[1], acc[f]);
      }
    }
    buf ^= 1;
  }
#undef STAGE

  const int b  = m0 >> 12;
  const int sb = m0 & (S_LEN - 1);
  if (wc == 0) {
#pragma unroll
    for (int f = 0; f < 6; ++f)
#pragma unroll
      for (int r = 0; r < 4; ++r) {
        const int row = m0 + wr * 16 + quad * 4 + r;
        if (f < 4) Qb[(size_t)row * DD + f * 16 + ln] = f2bf(acc[f][r]);
        else       Kb[(size_t)row * DD + (f - 4) * 16 + ln] = f2bf(acc[f][r]);
      }
  } else {
#pragma unroll
    for (int f = 0; f < 2; ++f)
#pragma unroll
      for (int r = 0; r < 4; ++r) {
        const int row = m0 + wr * 16 + quad * 4 + r;
        Kb[(size_t)row * DD + 32 + f * 16 + ln] = f2bf(acc[f][r]);
      }
#pragma unroll
    for (int f = 2; f < 6; ++f)
#pragma unroll
      for (int r = 0; r < 4; ++r) {
        const int d = (f - 2) * 16 + quad * 4 + r;
        Vt[((size_t)b * DD + d) * S_LEN + sb + wr * 16 + ln] = f2bf(acc[f][r]);
      }
  }
}

// ======================= Kernel 2: causal flash attention =======================
// Round 10: single-band blocks, grid 512, and the PROVEN register shape.
// Round 8/9 post-mortem: declaring launch_bounds (1024,4)/(512,4) clamped the
// allocator to 64 VGPR (gfx950 occupancy steps halve at 64/128/256) and
// spilled the K/V fragments -> 300-500 MB scratch traffic. Hardware residency
// follows ACTUAL VGPR count, so keep the (512,2) build (120 VGPR, no spill);
// with grid=512 and LDS 78,848 B, 2 blocks/CU co-reside (16 waves x 120 VGPR
// = 1920 <= 2048/CU; 2 x 78,848 <= 163,840 LDS). Blocks G and G+256 carry
// complementary bands (jj, 127-jj) for balanced per-CU work.
#define PSTRW 76

__global__ __launch_bounds__(512, 2) void attn_kernel(
    const short* __restrict__ Qb, const short* __restrict__ Kb,
    const short* __restrict__ Vt, float* __restrict__ out) {
  __shared__ float sbuf[8][32 * PSTRW];
  __shared__ float llds[8][32];

  const int tid  = threadIdx.x;
  const int w    = tid >> 6;
  const int lane = tid & 63;
  const int ln   = lane & 15;
  const int quad = lane >> 4;
  const int g    = blockIdx.x;
  const int u    = g & 255;
  const int half = g >> 8;
  const int b    = u & 3;
  const int jj   = u >> 2;
  const int band = half ? (127 - jj) : jj;
  const short* Kbase = Kb + (size_t)b * S_LEN * DD;
  const short* Vbase = Vt + (size_t)b * DD * S_LEN;
  float* pw = &sbuf[w][0];
  const float4v zz = {0.f, 0.f, 0.f, 0.f};

  const int qb  = band * 32;
  const int qg0 = b * S_LEN + qb;

  short8 aQ[2][2];
#pragma unroll
  for (int rfi = 0; rfi < 2; ++rfi)
#pragma unroll
    for (int h = 0; h < 2; ++h)
      aQ[rfi][h] = *(const short8*)(Qb + (size_t)(qg0 + rfi * 16 + ln) * DD + h * 32 + quad * 8);

  float4v o[2][4];
  float lp[2][4];
#pragma unroll
  for (int rfi = 0; rfi < 2; ++rfi)
#pragma unroll
    for (int d = 0; d < 4; ++d) { o[rfi][d] = zz; lp[rfi][d] = 0.f; }

  const int T = (qb + 95) >> 6;

  short8 Kc[4][2], Kn[4][2];
#pragma unroll
  for (int c = 0; c < 4; ++c)
#pragma unroll
    for (int h = 0; h < 2; ++h)
      Kc[c][h] = *(const short8*)(Kbase + (size_t)(w * 64 + c * 16 + ln) * DD + h * 32 + quad * 8);

  for (int it = w; it < T; it += 8) {
    const int kv0 = it * 64;
    short8 Vc[4][2];
#pragma unroll
    for (int d = 0; d < 4; ++d)
#pragma unroll
      for (int h = 0; h < 2; ++h)
        Vc[d][h] = *(const short8*)(Vbase + (size_t)(d * 16 + ln) * S_LEN + kv0 + h * 32 + quad * 8);

    float4v s[2][4];
#pragma unroll
    for (int rfi = 0; rfi < 2; ++rfi)
#pragma unroll
      for (int c = 0; c < 4; ++c) {
        s[rfi][c] = MFMA16(aQ[rfi][0], Kc[c][0], zz);
        s[rfi][c] = MFMA16(aQ[rfi][1], Kc[c][1], s[rfi][c]);
      }

    const int kvn = (it + 8 < T) ? (it + 8) * 64 : 0;
#pragma unroll
    for (int c = 0; c < 4; ++c)
#pragma unroll
      for (int h = 0; h < 2; ++h)
        Kn[c][h] = *(const short8*)(Kbase + (size_t)(kvn + c * 16 + ln) * DD + h * 32 + quad * 8);

    // P = exp2(S) (scores pre-scaled to log2 domain); single v_exp_f32 each.
    // Mask branch is wave-uniform: only the diagonal tile takes it.
    if ((kv0 + 63) > qb) {
#pragma unroll
      for (int rfi = 0; rfi < 2; ++rfi)
#pragma unroll
        for (int c = 0; c < 4; ++c)
#pragma unroll
          for (int r = 0; r < 4; ++r) {
            float e = __builtin_amdgcn_exp2f(fminf(s[rfi][c][r], 60.0f));
            if (kv0 + c * 16 + ln > qb + rfi * 16 + quad * 4 + r) e = 0.f;
            s[rfi][c][r] = e;
          }
    } else {
#pragma unroll
      for (int rfi = 0; rfi < 2; ++rfi)
#pragma unroll
        for (int c = 0; c < 4; ++c)
#pragma unroll
          for (int r = 0; r < 4; ++r)
            s[rfi][c][r] = __builtin_amdgcn_exp2f(fminf(s[rfi][c][r], 60.0f));
    }

#pragma unroll
    for (int rfi = 0; rfi < 2; ++rfi) {
#pragma unroll
      for (int r = 0; r < 4; ++r)
        lp[rfi][r] += s[rfi][0][r] + s[rfi][1][r] + s[rfi][2][r] + s[rfi][3][r];
#pragma unroll
      for (int c = 0; c < 4; ++c)
#pragma unroll
        for (int r = 0; r < 4; ++r)
          pw[(rfi * 16 + quad * 4 + r) * PSTRW + c * 16 + ln] = s[rfi][c][r];
    }
    asm volatile("s_waitcnt lgkmcnt(0)" ::: "memory");
    short8 aP[2][2];
#pragma unroll
    for (int rfi = 0; rfi < 2; ++rfi)
#pragma unroll
      for (int h = 0; h < 2; ++h) {
        const float4v lo = *(const float4v*)&pw[(rfi * 16 + ln) * PSTRW + h * 32 + quad * 8];
        const float4v hi = *(const float4v*)&pw[(rfi * 16 + ln) * PSTRW + h * 32 + quad * 8 + 4];
        aP[rfi][h] = cvt8(lo, hi);
      }
#pragma unroll
    for (int rfi = 0; rfi < 2; ++rfi)
#pragma unroll
      for (int d = 0; d < 4; ++d) {
        o[rfi][d] = MFMA16(aP[rfi][0], Vc[d][0], o[rfi][d]);
        o[rfi][d] = MFMA16(aP[rfi][1], Vc[d][1], o[rfi][d]);
      }
#pragma unroll
    for (int c = 0; c < 4; ++c)
#pragma unroll
      for (int h = 0; h < 2; ++h)
        Kc[c][h] = Kn[c][h];
  }

#pragma unroll
  for (int rfi = 0; rfi < 2; ++rfi)
#pragma unroll
    for (int r = 0; r < 4; ++r) {
      float lr = lp[rfi][r];
      lr += __shfl_xor(lr, 1);
      lr += __shfl_xor(lr, 2);
      lr += __shfl_xor(lr, 4);
      lr += __shfl_xor(lr, 8);
      if (ln == 0) llds[w][rfi * 16 + quad * 4 + r] = lr;
#pragma unroll
      for (int d = 0; d < 4; ++d)
        pw[(rfi * 16 + quad * 4 + r) * 64 + d * 16 + ln] = o[rfi][d][r];
    }
  __syncthreads();

#pragma unroll
  for (int jx = 0; jx < 4; ++jx) {
    const int idx = tid + jx * 512;
    const int row = idx >> 6, col = idx & 63;
    float sum = 0.f, lt = 0.f;
#pragma unroll
    for (int wi = 0; wi < 8; ++wi) {
      sum += sbuf[wi][row * 64 + col];
      lt  += llds[wi][row];
    }
    out[(size_t)(qg0 + row) * DD + col] = sum * __builtin_amdgcn_rcpf(lt);
  }
}

extern "C" void kernel_launch(void* const* d_in, const int* in_sizes, int n_in,
                              void* d_out, int out_size, void* d_ws, size_t ws_size,
                              hipStream_t stream) {
  const float* x  = (const float*)d_in[0];
  const float* Wq = (const float*)d_in[1];
  const float* Wk = (const float*)d_in[2];
  const float* Wv = (const float*)d_in[3];

  short* Qb  = (short*)d_ws;                       // 2 MB
  short* Kb  = Qb + (size_t)NROWS * DD;            // 2 MB
  short* Vt  = Kb + (size_t)NROWS * DD;            // 2 MB  [b][d][s]
  short* Wb2 = Vt + (size_t)NROWS * DD;            // 384 KB panels

  wcvt_kernel<<<dim3(96), dim3(256), 0, stream>>>(Wq, Wk, Wv, Wb2);
  qkv_kernel<<<dim3(NROWS / 32), dim3(256), 0, stream>>>(x, Wb2, Qb, Kb, Vt);
  attn_kernel<<<dim3(NBATCH * 128), dim3(512), 0, stream>>>(Qb, Kb, Vt, (float*)d_out);
}

// Round 4
// 156.262 us; speedup vs baseline: 1.5535x; 1.0171x over previous
//
#include <hip/hip_runtime.h>
#include <hip/hip_bf16.h>
#include <stdint.h>

typedef __attribute__((ext_vector_type(8))) short  short8;   // 8 bf16 (4 VGPR) MFMA A/B frag
typedef __attribute__((ext_vector_type(4))) short  short4v;
typedef __attribute__((ext_vector_type(4))) float  float4v;  // MFMA C/D frag

#define MFMA16(a, b, c) __builtin_amdgcn_mfma_f32_16x16x32_bf16((a), (b), (c), 0, 0, 0)

#define S_LEN  4096
#define NBATCH 4
#define EMB    1024
#define DD     64
#define NROWS  (NBATCH * S_LEN)  // 16384
#define SCL2   0.1803368801111204f  // (1/sqrt(64)) * log2(e), folded into Wq at wcvt

#define AS1 const __attribute__((address_space(1))) unsigned int*
#define AS3 __attribute__((address_space(3))) unsigned int*

static __device__ __forceinline__ short f2bf(float f) {
  uint32_t u = __float_as_uint(f);
  return (short)((u + 0x7FFFu + ((u >> 16) & 1u)) >> 16);
}
static __device__ __forceinline__ unsigned pk2(float a, float b) {
  union { __hip_bfloat162 h; unsigned u; } z;
  z.h = __float22bfloat162_rn(make_float2(a, b));
  return z.u;
}
static __device__ __forceinline__ short8 cvt8(float4v a, float4v b) {
  union { unsigned u[4]; short8 s; } z;
  z.u[0] = pk2(a[0], a[1]); z.u[1] = pk2(a[2], a[3]);
  z.u[2] = pk2(b[0], b[1]); z.u[3] = pk2(b[2], b[3]);
  return z.s;
}

// ============ Kernel 0: W fp32 -> bf16, reordered into 32-k panels ============
// Wb2 layout: [32 panels][192 rows][32 k] bf16; rows 0-63=Wq (pre-scaled by
// SCL2 -> scores arrive in log2 domain), 64-127=Wk, 128-191=Wv.
__global__ void wcvt_kernel(const float* __restrict__ Wq, const float* __restrict__ Wk,
                            const float* __restrict__ Wv, short* __restrict__ Wb2) {
  const int t   = blockIdx.x * 256 + threadIdx.x;  // 0..24575, 8 elems each
  const int row = t >> 7;
  const int k   = (t & 127) * 8;
  const float* src = (row < 64) ? (Wq + (size_t)row * EMB)
                   : (row < 128) ? (Wk + (size_t)(row - 64) * EMB)
                                 : (Wv + (size_t)(row - 128) * EMB);
  const float sc = (row < 64) ? SCL2 : 1.0f;
  float4v a = *(const float4v*)(src + k);
  float4v b = *(const float4v*)(src + k + 4);
#pragma unroll
  for (int i = 0; i < 4; ++i) { a[i] *= sc; b[i] *= sc; }
  *(short8*)(Wb2 + (((k >> 5) * 192 + row) << 5) + (k & 31)) = cvt8(a, b);
}

// ======================= Kernel 1: QKV projection GEMM =======================
// m97-style async GEMM: 512 blocks x 256 thr (2/CU), M-tile 32, BK=64.
// Both x (fp32) and W panels (bf16) staged via global_load_lds width=16 into
// double-buffered LDS; one barrier/step, next-stage DMA issued AFTER the
// barrier so it overlaps compute. (unchanged)
__global__ __launch_bounds__(256, 2) void qkv_kernel(
    const float* __restrict__ x, const short* __restrict__ Wb2,
    short* __restrict__ Qb, short* __restrict__ Kb, short* __restrict__ Vt) {
  __shared__ float As[2][2048];   // 2 x 8 KB  (32 rows x 64 k fp32, slot order)
  __shared__ short Bs[2][12288];  // 2 x 24 KB (2 panels x 192 x 32 bf16, identity)

  const int tid  = threadIdx.x;
  const int w    = tid >> 6;
  const int lane = tid & 63;
  const int ln   = lane & 15;
  const int quad = lane >> 4;
  const int m0   = blockIdx.x * 32;
  const int wr   = w & 1;
  const int wc   = w >> 1;

  const int tA0 = 2 * w, tA1 = 2 * w + 1;
  const float* xA0 = x + (size_t)(m0 + ((tA0 >> 2) << 4) + (lane >> 2)) * EMB
                       + ((tA0 & 3) * 4 + (lane & 3)) * 4;
  const float* xA1 = x + (size_t)(m0 + ((tA1 >> 2) << 4) + (lane >> 2)) * EMB
                       + ((tA1 & 3) * 4 + (lane & 3)) * 4;
  const short* wB = Wb2 + (size_t)(6 * w) * 512 + lane * 8;

#define STAGE(S, BUF) do {                                                      \
    __builtin_amdgcn_global_load_lds((AS1)(xA0 + (S) * 64),                     \
        (AS3)&As[BUF][tA0 * 256], 16, 0, 0);                                    \
    __builtin_amdgcn_global_load_lds((AS1)(xA1 + (S) * 64),                     \
        (AS3)&As[BUF][tA1 * 256], 16, 0, 0);                                    \
    _Pragma("unroll")                                                           \
    for (int j = 0; j < 6; ++j)                                                 \
      __builtin_amdgcn_global_load_lds((AS1)(wB + (size_t)(S) * 12288 + j * 512),\
          (AS3)&Bs[BUF][(6 * w + j) * 512], 16, 0, 0);                          \
  } while (0)

  const float4v zz = {0.f, 0.f, 0.f, 0.f};
  float4v acc[6] = {zz, zz, zz, zz, zz, zz};

  STAGE(0, 0);
  int buf = 0;
  for (int s = 0; s < 16; ++s) {
    __syncthreads();                       // drains this buf's DMA (vmcnt 0)
    if (s + 1 < 16) STAGE(s + 1, buf ^ 1); // overlaps with compute below
    short8 aF[2];
#pragma unroll
    for (int h = 0; h < 2; ++h) {
      const int ai = (wr * 4 + 2 * h + (quad >> 1)) * 256 + (ln * 4 + (quad & 1) * 2) * 4;
      const float4v lo = *(const float4v*)&As[buf][ai];
      const float4v hi = *(const float4v*)&As[buf][ai + 4];
      aF[h] = cvt8(lo, hi);
    }
#pragma unroll
    for (int f = 0; f < 6; ++f) {
      const int cf = wc * 6 + f;
      const short8 b0 = *(const short8*)&Bs[buf][(cf * 16 + ln) * 32 + quad * 8];
      const short8 b1 = *(const short8*)&Bs[buf][6144 + (cf * 16 + ln) * 32 + quad * 8];
      if (wc == 0 || f < 2) {
        acc[f] = MFMA16(aF[0], b0, acc[f]);
        acc[f] = MFMA16(aF[1], b1, acc[f]);
      } else {  // V frags: operand swap -> transposed output
        acc[f] = MFMA16(b0, aF[0], acc[f]);
        acc[f] = MFMA16(b1, aF[1], acc[f]);
      }
    }
    buf ^= 1;
  }
#undef STAGE

  const int b  = m0 >> 12;
  const int sb = m0 & (S_LEN - 1);
  if (wc == 0) {
#pragma unroll
    for (int f = 0; f < 6; ++f)
#pragma unroll
      for (int r = 0; r < 4; ++r) {
        const int row = m0 + wr * 16 + quad * 4 + r;
        if (f < 4) Qb[(size_t)row * DD + f * 16 + ln] = f2bf(acc[f][r]);
        else       Kb[(size_t)row * DD + (f - 4) * 16 + ln] = f2bf(acc[f][r]);
      }
  } else {
#pragma unroll
    for (int f = 0; f < 2; ++f)
#pragma unroll
      for (int r = 0; r < 4; ++r) {
        const int row = m0 + wr * 16 + quad * 4 + r;
        Kb[(size_t)row * DD + 32 + f * 16 + ln] = f2bf(acc[f][r]);
      }
#pragma unroll
    for (int f = 2; f < 6; ++f)
#pragma unroll
      for (int r = 0; r < 4; ++r) {
        const int d = (f - 2) * 16 + quad * 4 + r;
        Vt[((size_t)b * DD + d) * S_LEN + sb + wr * 16 + ln] = f2bf(acc[f][r]);
      }
  }
}

// ======================= Kernel 2: causal flash attention =======================
// Round 11: register diet to unlock 2-block/CU co-residency.
// Round 3 post-mortem: occupancy stuck at 19% with grid 512 because the
// unified VGPR+AGPR total (~104 arch + ~32 acc = ~136) exceeds 128, capping
// HW at 3 waves/SIMD -> a second 8-wave block (2 waves/SIMD) can't fit.
// Fix: drop the Kn K-prefetch double buffer (-16 regs, -16 v_movs/iter, no
// dummy tail loads); K is loaded at iteration top, latency covered by the
// doubled TLP this enables. PSTRW 76->68 (same bank profile, stride = 4 mod
// 32) cuts LDS to 70,656 B/block, removing any granularity doubt.
// Keep (512,2): cap 256, lean allocation -- never declare a 128 cap (the
// allocator splits 64 arch + 64 acc and spills; rounds 1-2).
#define PSTRW 68

__global__ __launch_bounds__(512, 2) void attn_kernel(
    const short* __restrict__ Qb, const short* __restrict__ Kb,
    const short* __restrict__ Vt, float* __restrict__ out) {
  __shared__ float sbuf[8][32 * PSTRW];
  __shared__ float llds[8][32];

  const int tid  = threadIdx.x;
  const int w    = tid >> 6;
  const int lane = tid & 63;
  const int ln   = lane & 15;
  const int quad = lane >> 4;
  const int g    = blockIdx.x;
  const int u    = g & 255;
  const int half = g >> 8;
  const int b    = u & 3;
  const int jj   = u >> 2;
  const int band = half ? (127 - jj) : jj;
  const short* Kbase = Kb + (size_t)b * S_LEN * DD;
  const short* Vbase = Vt + (size_t)b * DD * S_LEN;
  float* pw = &sbuf[w][0];
  const float4v zz = {0.f, 0.f, 0.f, 0.f};

  const int qb  = band * 32;
  const int qg0 = b * S_LEN + qb;

  short8 aQ[2][2];
#pragma unroll
  for (int rfi = 0; rfi < 2; ++rfi)
#pragma unroll
    for (int h = 0; h < 2; ++h)
      aQ[rfi][h] = *(const short8*)(Qb + (size_t)(qg0 + rfi * 16 + ln) * DD + h * 32 + quad * 8);

  float4v o[2][4];
  float lp[2][4];
#pragma unroll
  for (int rfi = 0; rfi < 2; ++rfi)
#pragma unroll
    for (int d = 0; d < 4; ++d) { o[rfi][d] = zz; lp[rfi][d] = 0.f; }

  const int T = (qb + 95) >> 6;

  for (int it = w; it < T; it += 8) {
    const int kv0 = it * 64;
    // K for this tile (single-buffered; issued first so QK's wait is short)
    short8 Kc[4][2];
#pragma unroll
    for (int c = 0; c < 4; ++c)
#pragma unroll
      for (int h = 0; h < 2; ++h)
        Kc[c][h] = *(const short8*)(Kbase + (size_t)(kv0 + c * 16 + ln) * DD + h * 32 + quad * 8);
    // V issued second; stays in flight through QK^T + exp
    short8 Vc[4][2];
#pragma unroll
    for (int d = 0; d < 4; ++d)
#pragma unroll
      for (int h = 0; h < 2; ++h)
        Vc[d][h] = *(const short8*)(Vbase + (size_t)(d * 16 + ln) * S_LEN + kv0 + h * 32 + quad * 8);

    float4v s[2][4];
#pragma unroll
    for (int rfi = 0; rfi < 2; ++rfi)
#pragma unroll
      for (int c = 0; c < 4; ++c) {
        s[rfi][c] = MFMA16(aQ[rfi][0], Kc[c][0], zz);
        s[rfi][c] = MFMA16(aQ[rfi][1], Kc[c][1], s[rfi][c]);
      }

    // P = exp2(S) (scores pre-scaled to log2 domain); single v_exp_f32 each.
    // Mask branch is wave-uniform: only the diagonal tile takes it.
    if ((kv0 + 63) > qb) {
#pragma unroll
      for (int rfi = 0; rfi < 2; ++rfi)
#pragma unroll
        for (int c = 0; c < 4; ++c)
#pragma unroll
          for (int r = 0; r < 4; ++r) {
            float e = __builtin_amdgcn_exp2f(fminf(s[rfi][c][r], 60.0f));
            if (kv0 + c * 16 + ln > qb + rfi * 16 + quad * 4 + r) e = 0.f;
            s[rfi][c][r] = e;
          }
    } else {
#pragma unroll
      for (int rfi = 0; rfi < 2; ++rfi)
#pragma unroll
        for (int c = 0; c < 4; ++c)
#pragma unroll
          for (int r = 0; r < 4; ++r)
            s[rfi][c][r] = __builtin_amdgcn_exp2f(fminf(s[rfi][c][r], 60.0f));
    }

#pragma unroll
    for (int rfi = 0; rfi < 2; ++rfi) {
#pragma unroll
      for (int r = 0; r < 4; ++r)
        lp[rfi][r] += s[rfi][0][r] + s[rfi][1][r] + s[rfi][2][r] + s[rfi][3][r];
#pragma unroll
      for (int c = 0; c < 4; ++c)
#pragma unroll
        for (int r = 0; r < 4; ++r)
          pw[(rfi * 16 + quad * 4 + r) * PSTRW + c * 16 + ln] = s[rfi][c][r];
    }
    asm volatile("s_waitcnt lgkmcnt(0)" ::: "memory");
    short8 aP[2][2];
#pragma unroll
    for (int rfi = 0; rfi < 2; ++rfi)
#pragma unroll
      for (int h = 0; h < 2; ++h) {
        const float4v lo = *(const float4v*)&pw[(rfi * 16 + ln) * PSTRW + h * 32 + quad * 8];
        const float4v hi = *(const float4v*)&pw[(rfi * 16 + ln) * PSTRW + h * 32 + quad * 8 + 4];
        aP[rfi][h] = cvt8(lo, hi);
      }
#pragma unroll
    for (int rfi = 0; rfi < 2; ++rfi)
#pragma unroll
      for (int d = 0; d < 4; ++d) {
        o[rfi][d] = MFMA16(aP[rfi][0], Vc[d][0], o[rfi][d]);
        o[rfi][d] = MFMA16(aP[rfi][1], Vc[d][1], o[rfi][d]);
      }
  }

#pragma unroll
  for (int rfi = 0; rfi < 2; ++rfi)
#pragma unroll
    for (int r = 0; r < 4; ++r) {
      float lr = lp[rfi][r];
      lr += __shfl_xor(lr, 1);
      lr += __shfl_xor(lr, 2);
      lr += __shfl_xor(lr, 4);
      lr += __shfl_xor(lr, 8);
      if (ln == 0) llds[w][rfi * 16 + quad * 4 + r] = lr;
#pragma unroll
      for (int d = 0; d < 4; ++d)
        pw[(rfi * 16 + quad * 4 + r) * 64 + d * 16 + ln] = o[rfi][d][r];
    }
  __syncthreads();

#pragma unroll
  for (int jx = 0; jx < 4; ++jx) {
    const int idx = tid + jx * 512;
    const int row = idx >> 6, col = idx & 63;
    float sum = 0.f, lt = 0.f;
#pragma unroll
    for (int wi = 0; wi < 8; ++wi) {
      sum += sbuf[wi][row * 64 + col];
      lt  += llds[wi][row];
    }
    out[(size_t)(qg0 + row) * DD + col] = sum * __builtin_amdgcn_rcpf(lt);
  }
}

extern "C" void kernel_launch(void* const* d_in, const int* in_sizes, int n_in,
                              void* d_out, int out_size, void* d_ws, size_t ws_size,
                              hipStream_t stream) {
  const float* x  = (const float*)d_in[0];
  const float* Wq = (const float*)d_in[1];
  const float* Wk = (const float*)d_in[2];
  const float* Wv = (const float*)d_in[3];

  short* Qb  = (short*)d_ws;                       // 2 MB
  short* Kb  = Qb + (size_t)NROWS * DD;            // 2 MB
  short* Vt  = Kb + (size_t)NROWS * DD;            // 2 MB  [b][d][s]
  short* Wb2 = Vt + (size_t)NROWS * DD;            // 384 KB panels

  wcvt_kernel<<<dim3(96), dim3(256), 0, stream>>>(Wq, Wk, Wv, Wb2);
  qkv_kernel<<<dim3(NROWS / 32), dim3(256), 0, stream>>>(x, Wb2, Qb, Kb, Vt);
  attn_kernel<<<dim3(NBATCH * 128), dim3(512), 0, stream>>>(Qb, Kb, Vt, (float*)d_out);
}